// Round 30
// baseline (267.728 us; speedup 1.0000x reference)
//
#include <hip/hip_runtime.h>
#include <hip/hip_bf16.h>
#include <math.h>

#define B_    4096
#define V_    9
#define N_    (B_*V_)          // 36864 nodes
#define EK_   (B_*V_*(V_-1))   // 294912 kept edges
#define TPB   512
#define FS    136              // fragment row stride (ushorts): 272 B, 16B-aligned

typedef unsigned short ushort_t;
typedef __attribute__((ext_vector_type(8))) short bf16x8;   // 8 bf16 (4 VGPRs)
typedef __attribute__((ext_vector_type(4))) float f32x4;    // 4 f32 / 16B chunk

__device__ __forceinline__ float b2f(ushort_t u) {
    union { unsigned int i; float f; } x; x.i = ((unsigned int)u) << 16; return x.f;
}
__device__ __forceinline__ ushort_t f2b(float f) {
    union { float f; unsigned int i; } x; x.f = f;
    unsigned int r = x.i + 0x7FFFu + ((x.i >> 16) & 1u);
    return (ushort_t)(r >> 16);
}
__device__ __forceinline__ float lo16(unsigned int u) {
    union { unsigned int i; float f; } x; x.i = u << 16; return x.f;
}
__device__ __forceinline__ float hi16(unsigned int u) {
    union { unsigned int i; float f; } x; x.i = u & 0xFFFF0000u; return x.f;
}
union bfu { bf16x8 v; unsigned int u[4]; };

// ---------------------------------------------------------------------------
// MFMA GEMM for the MLP chain (measured r29: chain ~50 us).  Layouts proven.
// ---------------------------------------------------------------------------
__global__ __launch_bounds__(256) void gemm_mfma_kernel(
    const ushort_t* __restrict__ Ab, const ushort_t* __restrict__ Bt,
    const float* __restrict__ bias, ushort_t* __restrict__ outb,
    int K, int N, int Nstride, int act, int nblk)
{
    const int bm   = blockIdx.x / nblk;
    const int bn   = blockIdx.x - bm * nblk;
    const int row0 = bm * 128 + (threadIdx.x >> 6) * 32;
    const int n0   = bn * 64;
    const int lane = threadIdx.x & 63;
    const int l15  = lane & 15;
    const int kg   = lane >> 4;

    f32x4 acc[2][4] = {};
    for (int k0 = 0; k0 < K; k0 += 32) {
        bf16x8 a0 = *(const bf16x8*)&Ab[(row0 + l15) * K + k0 + kg * 8];
        bf16x8 a1 = *(const bf16x8*)&Ab[(row0 + 16 + l15) * K + k0 + kg * 8];
        #pragma unroll
        for (int nt = 0; nt < 4; ++nt) {
            bf16x8 bfr = *(const bf16x8*)&Bt[(n0 + nt * 16 + l15) * K + k0 + kg * 8];
            acc[0][nt] = __builtin_amdgcn_mfma_f32_16x16x32_bf16(a0, bfr, acc[0][nt], 0, 0, 0);
            acc[1][nt] = __builtin_amdgcn_mfma_f32_16x16x32_bf16(a1, bfr, acc[1][nt], 0, 0, 0);
        }
    }
    #pragma unroll
    for (int m = 0; m < 2; ++m)
        #pragma unroll
        for (int nt = 0; nt < 4; ++nt) {
            int col = n0 + nt * 16 + l15;
            if (col < N) {
                float bv = bias[col];
                #pragma unroll
                for (int r = 0; r < 4; ++r) {
                    int row = row0 + m * 16 + kg * 4 + r;
                    float v = acc[m][nt][r] + bv;
                    if (act) v = tanhf(v);
                    outb[row * Nstride + col] = f2b(v);
                }
            }
        }
}

// ---------------------------------------------------------------------------
// Conv-weight prep (unchanged from r28/r29)
// ---------------------------------------------------------------------------
__global__ __launch_bounds__(256) void prep_weights_kernel(
    const float* __restrict__ c0_wq, const float* __restrict__ c0_wk,
    const float* __restrict__ c0_wv, const float* __restrict__ c0_we,
    const float* __restrict__ c0_weo,
    const float* __restrict__ c1_wq, const float* __restrict__ c1_wk,
    const float* __restrict__ c1_wv, const float* __restrict__ c1_we,
    const float* __restrict__ c1_weo,
    ushort_t* __restrict__ wb)
{
    int idx = blockIdx.x * 256 + threadIdx.x;
    if (idx < 40960) {
        int buf = idx / 5120, r = idx - buf * 5120;
        int n = r / 40, m = r - n * 40;
        const float* src; int K;
        switch (buf) {
            case 0: src = c0_wq; K = 13; break;
            case 1: src = c0_wk; K = 13; break;
            case 2: src = c0_wv; K = 13; break;
            case 3: src = c0_we; K = 5;  break;
            case 4: src = c1_wq; K = 32; break;
            case 5: src = c1_wk; K = 32; break;
            case 6: src = c1_wv; K = 32; break;
            default: src = c1_we; K = 32; break;
        }
        wb[idx] = (m < K) ? f2b(src[m * 128 + n]) : (ushort_t)0;
    } else if (idx < 47616) {
        int r2 = idx - 40960;
        int which = r2 / 3328, r = r2 - which * 3328;
        int c = r / 104, row = r - c * 104;
        float v = 0.f;
        if (which) {
            if (row < 96) v = c1_weo[row * 32 + c];
        } else {
            if (row < 13)                    v = c0_weo[row * 32 + c];
            else if (row >= 16 && row < 29)  v = c0_weo[(13 + row - 16) * 32 + c];
            else if (row >= 32 && row < 37)  v = c0_weo[(26 + row - 32) * 32 + c];
        }
        wb[idx] = f2b(v);
    }
}

// ---------------------------------------------------------------------------
// MLP prep (unchanged from r29)
// ---------------------------------------------------------------------------
__global__ __launch_bounds__(256) void prep_mlp_kernel(
    const float* __restrict__ w0, const float* __restrict__ w1,
    const float* __restrict__ w2, const float* __restrict__ we,
    const float* __restrict__ wn, const float* __restrict__ latent,
    ushort_t* __restrict__ bt, ushort_t* __restrict__ latb)
{
    int idx = blockIdx.x * 256 + threadIdx.x;
    if (idx < 16384) {
        int n = idx >> 7, k = idx & 127;
        bt[idx] = f2b(w0[k * 128 + n]);
    } else if (idx < 49152) {
        int r = idx - 16384, n = r >> 7, k = r & 127;
        bt[idx] = f2b(w1[k * 256 + n]);
    } else if (idx < 180224) {
        int r = idx - 49152, n = r >> 8, k = r & 255;
        bt[idx] = f2b(w2[k * 512 + n]);
    } else if (idx < 409600) {
        int r = idx - 180224, n = r >> 9, k = r & 511;
        bt[idx] = (n < 405) ? f2b(we[k * 405 + n]) : (ushort_t)0;
    } else if (idx < 475136) {
        int r = idx - 409600, n = r >> 9, k = r & 511;
        bt[idx] = (n < 117) ? f2b(wn[k * 117 + n]) : (ushort_t)0;
    } else if (idx < 999424) {
        int r = idx - 475136;
        latb[r] = f2b(latent[r]);
    }
}

// ---------------------------------------------------------------------------
// MFMA conv layer, vectorized-LDS edition.  MFMA fragment math identical to
// the r28/r29 winner; P2a/P3 read b128 + unpack (96->12 / 72->27 LDS issues
// per task); P3 split into per-(j,h,d8) partials + reduce.
// ---------------------------------------------------------------------------
template <int XD, int ED2>
__device__ __forceinline__ void conv_layer(
    ushort_t* xsb, ushort_t* esb,
    const ushort_t* __restrict__ wq_p, const ushort_t* __restrict__ wk_p,
    const ushort_t* __restrict__ wv_p, const ushort_t* __restrict__ we_p,
    const ushort_t* __restrict__ weo_p,
    ushort_t* qb, ushort_t* kb, ushort_t* vb,
    ushort_t* ehb, float* en, float* xn, float* la, float* pbuf, int tid)
{
    const int wv_  = tid >> 6;
    const int lane = tid & 63;
    const int l15  = lane & 15;
    const int kg   = lane >> 4;

    // P1 (merged): q,k (16 tasks) + v (8) + eh (48) = 72 wave-tasks
    for (int task = wv_; task < 72; task += 8) {
        if (task < 16) {
            int mat = task >> 3, nt = task & 7;
            bf16x8 a = *(const bf16x8*)&xsb[l15 * 40 + kg * 8];
            const ushort_t* wp = mat ? wk_p : wq_p;
            bf16x8 bf = *(const bf16x8*)&wp[(nt * 16 + l15) * 40 + kg * 8];
            f32x4 d = {0.f, 0.f, 0.f, 0.f};
            d = __builtin_amdgcn_mfma_f32_16x16x32_bf16(a, bf, d, 0, 0, 0);
            ushort_t* dst = mat ? kb : qb;
            #pragma unroll
            for (int r = 0; r < 4; ++r)
                dst[(kg * 4 + r) * FS + nt * 16 + l15] = f2b(d[r]);
        } else if (task < 24) {
            int nt = task - 16;
            bf16x8 a = *(const bf16x8*)&xsb[l15 * 40 + kg * 8];
            bf16x8 bf = *(const bf16x8*)&wv_p[(nt * 16 + l15) * 40 + kg * 8];
            f32x4 d = {0.f, 0.f, 0.f, 0.f};
            d = __builtin_amdgcn_mfma_f32_16x16x32_bf16(a, bf, d, 0, 0, 0);
            #pragma unroll
            for (int r = 0; r < 4; ++r)
                vb[(kg * 4 + r) * FS + nt * 16 + l15] = f2b(d[r]);
        } else {
            int t2 = task - 24, mt = t2 >> 3, nt = t2 & 7;
            bf16x8 a = *(const bf16x8*)&esb[(mt * 16 + l15) * 40 + kg * 8];
            bf16x8 bf = *(const bf16x8*)&we_p[(nt * 16 + l15) * 40 + kg * 8];
            f32x4 d = {0.f, 0.f, 0.f, 0.f};
            d = __builtin_amdgcn_mfma_f32_16x16x32_bf16(a, bf, d, 0, 0, 0);
            #pragma unroll
            for (int r = 0; r < 4; ++r)
                ehb[(mt * 16 + kg * 4 + r) * FS + nt * 16 + l15] = f2b(d[r]);
        }
    }
    __syncthreads();

    // P2a: logits, b128 reads + unpack
    for (int idx = tid; idx < 324; idx += TPB) {
        int le = idx >> 2, h = idx & 3;
        int i = le / 9, j = le - i * 9;
        float acc = 0.f;
        #pragma unroll
        for (int g = 0; g < 4; ++g) {
            bfu Q, Kf, E;
            Q.v  = *(const bf16x8*)&qb[j * FS + h * 32 + g * 8];
            Kf.v = *(const bf16x8*)&kb[i * FS + h * 32 + g * 8];
            E.v  = *(const bf16x8*)&ehb[le * FS + h * 32 + g * 8];
            #pragma unroll
            for (int w = 0; w < 4; ++w) {
                acc = fmaf(lo16(Q.u[w]), lo16(Kf.u[w]) + lo16(E.u[w]), acc);
                acc = fmaf(hi16(Q.u[w]), hi16(Kf.u[w]) + hi16(E.u[w]), acc);
            }
        }
        la[idx] = acc * 0.17677669529663687f;
    }
    __syncthreads();

    // P2b: segment softmax
    for (int s = tid; s < 36; s += TPB) {
        int j = s >> 2, h = s & 3;
        float m = -1e30f;
        #pragma unroll
        for (int i = 0; i < 9; ++i) m = fmaxf(m, la[(i * 9 + j) * 4 + h]);
        float ex[9], sum = 0.f;
        #pragma unroll
        for (int i = 0; i < 9; ++i) { ex[i] = __expf(la[(i * 9 + j) * 4 + h] - m); sum += ex[i]; }
        float inv = 1.f / (sum + 1e-16f);
        #pragma unroll
        for (int i = 0; i < 9; ++i) la[(i * 9 + j) * 4 + h] = ex[i] * inv;
    }
    __syncthreads();

    // P3a: partial aggregation per (j,h,d8) -> pbuf[h][j][d]
    for (int idx = tid; idx < 144; idx += TPB) {
        int j = idx >> 4, rem = idx & 15;
        int h = rem >> 2, dg = rem & 3;
        float a8[8];
        #pragma unroll
        for (int u = 0; u < 8; ++u) a8[u] = 0.f;
        #pragma unroll
        for (int i = 0; i < 9; ++i) {
            int le = i * 9 + j;
            float al = la[le * 4 + h];
            bfu Vf, E;
            Vf.v = *(const bf16x8*)&vb[i * FS + h * 32 + dg * 8];
            E.v  = *(const bf16x8*)&ehb[le * FS + h * 32 + dg * 8];
            #pragma unroll
            for (int w = 0; w < 4; ++w) {
                a8[w * 2]     = fmaf(al, lo16(Vf.u[w]) + lo16(E.u[w]), a8[w * 2]);
                a8[w * 2 + 1] = fmaf(al, hi16(Vf.u[w]) + hi16(E.u[w]), a8[w * 2 + 1]);
            }
        }
        #pragma unroll
        for (int u = 0; u < 8; ++u)
            pbuf[(h * 9 + j) * 32 + dg * 8 + u] = a8[u];
    }
    __syncthreads();

    // P3b: reduce over h -> xn (aliases qb; qb dead after P2a)
    for (int idx = tid; idx < 288; idx += TPB) {
        int j = idx >> 5, d = idx & 31;
        xn[idx] = 0.25f * (pbuf[j * 32 + d] + pbuf[288 + j * 32 + d] +
                           pbuf[576 + j * 32 + d] + pbuf[864 + j * 32 + d]);
    }
    __syncthreads();   // ehb reads done (en aliases ehb, written in P4)

    // P4: edge-MLP, A-frags direct from xsb/esb (unchanged)
    const int KS = (XD == 13) ? 2 : 3;
    for (int task = wv_; task < 12; task += 8) {
        int mt = task >> 1, nt = task & 1;
        int le = mt * 16 + l15;
        int i = le / 9, j = le - i * 9;
        f32x4 d = {0.f, 0.f, 0.f, 0.f};
        #pragma unroll
        for (int ks = 0; ks < KS; ++ks) {
            bf16x8 a;
            if (XD == 13) {
                if (ks == 0)
                    a = (kg < 2) ? *(const bf16x8*)&xsb[i * 40 + kg * 8]
                                 : *(const bf16x8*)&xsb[j * 40 + (kg - 2) * 8];
                else
                    a = *(const bf16x8*)&esb[le * 40 + kg * 8];
            } else {
                a = (ks == 0) ? *(const bf16x8*)&xsb[i * 40 + kg * 8]
                  : (ks == 1) ? *(const bf16x8*)&xsb[j * 40 + kg * 8]
                              : *(const bf16x8*)&esb[le * 40 + kg * 8];
            }
            bf16x8 bf = *(const bf16x8*)&weo_p[(nt * 16 + l15) * 104 + ks * 32 + kg * 8];
            d = __builtin_amdgcn_mfma_f32_16x16x32_bf16(a, bf, d, 0, 0, 0);
        }
        #pragma unroll
        for (int r = 0; r < 4; ++r) {
            int row = mt * 16 + kg * 4 + r;
            if (row < 81) en[row * 32 + nt * 16 + l15] = d[r];
        }
    }
    __syncthreads();
}

// ---------------------------------------------------------------------------
// Fused GNN.  LDS ~55.9 KB (2 blocks/CU), VGPR cap 64 (r28: 48, no spills).
// ---------------------------------------------------------------------------
__global__ __launch_bounds__(TPB, 4) void fused_gnn_kernel(
    const ushort_t* __restrict__ nlb,  // [B][120] bf16
    const ushort_t* __restrict__ elb,  // [B][408] bf16
    const ushort_t* __restrict__ wb,
    const float* __restrict__ ln0_g, const float* __restrict__ ln0_b,
    const float* __restrict__ ln1_g, const float* __restrict__ ln1_b,
    const float* __restrict__ w_feat, const float* __restrict__ w_eout,
    float* __restrict__ out)
{
    __shared__ __align__(16) ushort_t xsb[16 * 40];
    __shared__ __align__(16) ushort_t esb[96 * 40];
    __shared__ __align__(16) ushort_t qb[16 * FS];
    __shared__ __align__(16) ushort_t kb[16 * FS];
    __shared__ __align__(16) ushort_t vb[16 * FS];
    __shared__ __align__(16) ushort_t ehb[96 * FS];
    __shared__ __align__(16) float la[324];
    __shared__ __align__(16) float pbuf[4 * 9 * 32];
    __shared__ __align__(16) float wfT[10 * 32];   // w_feat^T [c][kk]
    __shared__ __align__(16) float weT[5 * 32];    // w_eout^T [c][kk]

    float* en = (float*)ehb;
    float* xn = (float*)qb;

    const int b   = blockIdx.x;
    const int tid = threadIdx.x;

    for (int idx = tid; idx < 16 * 40; idx += TPB) xsb[idx] = 0;
    for (int idx = tid; idx < 96 * 40; idx += TPB) esb[idx] = 0;
    for (int idx = tid; idx < 320; idx += TPB) {
        int c = idx >> 5, kk = idx & 31;
        wfT[idx] = w_feat[kk * 10 + c];
    }
    for (int idx = tid; idx < 160; idx += TPB) {
        int c = idx >> 5, kk = idx & 31;
        weT[idx] = w_eout[kk * 5 + c];
    }
    __syncthreads();
    for (int idx = tid; idx < 117; idx += TPB) {
        int node = idx / 13, m = idx - node * 13;
        xsb[node * 40 + m] = nlb[b * 120 + idx];
    }
    for (int idx = tid; idx < 405; idx += TPB) {
        int le = idx / 5, c = idx - le * 5;
        int i = le / 9, j = le - i * 9;
        esb[le * 40 + c] = f2b(0.5f * (b2f(elb[b * 408 + c * 81 + i * 9 + j]) +
                                       b2f(elb[b * 408 + c * 81 + j * 9 + i])));
    }
    __syncthreads();

    for (int layer = 0; layer < 3; ++layer) {
        if (layer == 0)
            conv_layer<13, 5>(xsb, esb,
                              wb + 0, wb + 5120, wb + 10240, wb + 15360, wb + 40960,
                              qb, kb, vb, ehb, en, xn, la, pbuf, tid);
        else
            conv_layer<32, 32>(xsb, esb,
                               wb + 20480, wb + 25600, wb + 30720, wb + 35840, wb + 44288,
                               qb, kb, vb, ehb, en, xn, la, pbuf, tid);

        // P5 (layers 0,1): x = leaky(LN(xn)) via shfl; e = leaky(en)
        if (layer < 2) {
            const float* g  = (layer == 0) ? ln0_g : ln1_g;
            const float* be = (layer == 0) ? ln0_b : ln1_b;
            if (tid < 288) {
                int j = tid >> 5, c = tid & 31;
                float v = xn[tid];
                float s = v, q = v * v;
                #pragma unroll
                for (int m = 1; m <= 16; m <<= 1) {
                    s += __shfl_xor(s, m, 64);
                    q += __shfl_xor(q, m, 64);
                }
                float mu  = s * (1.f / 32.f);
                float var = q * (1.f / 32.f) - mu * mu;
                float val = (v - mu) / sqrtf(var + 1e-5f);
                val = val * g[c] + be[c];
                xsb[j * 40 + c] = f2b((val > 0.f) ? val : 0.01f * val);
            }
            for (int idx = tid; idx < 648; idx += TPB) {
                int le = idx >> 3, cg = (idx & 7) * 4;
                f32x4 v = *(const f32x4*)&en[le * 32 + cg];
                #pragma unroll
                for (int u = 0; u < 4; ++u) {
                    float x = v[u];
                    esb[le * 40 + cg + u] = f2b((x > 0.f) ? x : 0.01f * x);
                }
            }
            __syncthreads();
        }
    }

    float* out_x  = out;                       // [36864,10]
    float* out_e  = out + 368640;              // [294912,5]
    float* out_ei = out + 1843200;             // [2,294912]
    float* out_b  = out + 2433024;             // [36864]

    for (int idx = tid; idx < 90; idx += TPB) {
        int j = idx / 10, c = idx - j * 10;
        float acc = 0.f;
        #pragma unroll
        for (int kg2 = 0; kg2 < 8; ++kg2) {
            f32x4 xv = *(const f32x4*)&xn[j * 32 + kg2 * 4];
            f32x4 wv = *(const f32x4*)&wfT[c * 32 + kg2 * 4];
            #pragma unroll
            for (int u = 0; u < 4; ++u) acc = fmaf(xv[u], wv[u], acc);
        }
        out_x[(b * 9 + j) * 10 + c] = acc;
    }
    for (int idx = tid; idx < 360; idx += TPB) {
        int r = idx / 5, c = idx - r * 5;
        int i = r >> 3, jj = r & 7;
        int j = jj + (jj >= i ? 1 : 0);
        const float* row = &en[(i * 9 + j) * 32];
        float acc = 0.f;
        #pragma unroll
        for (int kg2 = 0; kg2 < 8; ++kg2) {
            f32x4 ev = *(const f32x4*)&row[kg2 * 4];
            f32x4 wv = *(const f32x4*)&weT[c * 32 + kg2 * 4];
            #pragma unroll
            for (int u = 0; u < 4; ++u) acc = fmaf(ev[u], wv[u], acc);
        }
        out_e[(b * 72 + r) * 5 + c] = acc;
    }
    for (int idx = tid; idx < 72; idx += TPB) {
        int i = idx >> 3, jj = idx & 7;
        int j = jj + (jj >= i ? 1 : 0);
        out_ei[b * 72 + idx]          = (float)(b * 9 + i);
        out_ei[294912 + b * 72 + idx] = (float)(b * 9 + j);
    }
    for (int idx = tid; idx < 9; idx += TPB)
        out_b[b * 9 + idx] = (float)b;
}

// ---------------------------------------------------------------------------
extern "C" void kernel_launch(void* const* d_in, const int* in_sizes, int n_in,
                              void* d_out, int out_size, void* d_ws, size_t ws_size,
                              hipStream_t stream)
{
    const float* latent  = (const float*)d_in[0];
    const float* w_mlp0  = (const float*)d_in[1];
    const float* b_mlp0  = (const float*)d_in[2];
    const float* w_mlp1  = (const float*)d_in[3];
    const float* b_mlp1  = (const float*)d_in[4];
    const float* w_mlp2  = (const float*)d_in[5];
    const float* b_mlp2  = (const float*)d_in[6];
    const float* w_edges = (const float*)d_in[7];
    const float* b_edges = (const float*)d_in[8];
    const float* w_nodes = (const float*)d_in[9];
    const float* b_nodes = (const float*)d_in[10];
    const float* c0_wq   = (const float*)d_in[11];
    const float* c0_wk   = (const float*)d_in[12];
    const float* c0_wv   = (const float*)d_in[13];
    const float* c0_we   = (const float*)d_in[14];
    const float* c0_weo  = (const float*)d_in[15];
    const float* c1_wq   = (const float*)d_in[16];
    const float* c1_wk   = (const float*)d_in[17];
    const float* c1_wv   = (const float*)d_in[18];
    const float* c1_we   = (const float*)d_in[19];
    const float* c1_weo  = (const float*)d_in[20];
    const float* ln0_g   = (const float*)d_in[21];
    const float* ln0_b   = (const float*)d_in[22];
    const float* ln1_g   = (const float*)d_in[23];
    const float* ln1_b   = (const float*)d_in[24];
    const float* w_feat  = (const float*)d_in[25];
    const float* w_eout  = (const float*)d_in[26];

    // Workspace (ushort offsets; all 16B-aligned) -- unchanged from r29
    ushort_t* wsu  = (ushort_t*)d_ws;
    ushort_t* wb   = wsu;
    ushort_t* bt   = wsu + 47616;
    ushort_t* latb = wsu + 522752;
    ushort_t* h0b  = wsu + 1047040;
    ushort_t* h1b  = wsu + 1571328;
    ushort_t* h2b  = wsu + 2619904;
    ushort_t* elb  = wsu + 4717056;
    ushort_t* nlb  = wsu + 6388224;

    float* out = (float*)d_out;

    prep_weights_kernel<<<187, 256, 0, stream>>>(
        c0_wq, c0_wk, c0_wv, c0_we, c0_weo,
        c1_wq, c1_wk, c1_wv, c1_we, c1_weo, wb);
    prep_mlp_kernel<<<3904, 256, 0, stream>>>(
        w_mlp0, w_mlp1, w_mlp2, w_edges, w_nodes, latent, bt, latb);

    gemm_mfma_kernel<<<32 * 2, 256, 0, stream>>>(latb, bt + 0,      b_mlp0, h0b, 128, 128, 128, 1, 2);
    gemm_mfma_kernel<<<32 * 4, 256, 0, stream>>>(h0b,  bt + 16384,  b_mlp1, h1b, 128, 256, 256, 1, 4);
    gemm_mfma_kernel<<<32 * 8, 256, 0, stream>>>(h1b,  bt + 49152,  b_mlp2, h2b, 256, 512, 512, 1, 8);
    gemm_mfma_kernel<<<32 * 7, 256, 0, stream>>>(h2b,  bt + 180224, b_edges, elb, 512, 405, 408, 0, 7);
    gemm_mfma_kernel<<<32 * 2, 256, 0, stream>>>(h2b,  bt + 409600, b_nodes, nlb, 512, 117, 120, 0, 2);

    fused_gnn_kernel<<<B_, TPB, 0, stream>>>(nlb, elb, wb,
        ln0_g, ln0_b, ln1_g, ln1_b, w_feat, w_eout, out);
}

// Round 31
// 249.134 us; speedup vs baseline: 1.0746x; 1.0746x over previous
//
#include <hip/hip_runtime.h>
#include <hip/hip_bf16.h>
#include <math.h>

#define B_    4096
#define V_    9
#define N_    (B_*V_)          // 36864 nodes
#define EK_   (B_*V_*(V_-1))   // 294912 kept edges
#define TPB   512

typedef unsigned short ushort_t;
typedef __attribute__((ext_vector_type(8))) short bf16x8;   // 8 bf16 (4 VGPRs)
typedef __attribute__((ext_vector_type(4))) float f32x4;    // 4 f32 / 16B chunk

__device__ __forceinline__ float b2f(ushort_t u) {
    union { unsigned int i; float f; } x; x.i = ((unsigned int)u) << 16; return x.f;
}
__device__ __forceinline__ ushort_t f2b(float f) {
    union { float f; unsigned int i; } x; x.f = f;
    unsigned int r = x.i + 0x7FFFu + ((x.i >> 16) & 1u);
    return (ushort_t)(r >> 16);
}

// ---------------------------------------------------------------------------
// MFMA GEMM for the MLP chain (measured r29: chain ~50 us)
// ---------------------------------------------------------------------------
__global__ __launch_bounds__(256) void gemm_mfma_kernel(
    const ushort_t* __restrict__ Ab, const ushort_t* __restrict__ Bt,
    const float* __restrict__ bias, ushort_t* __restrict__ outb,
    int K, int N, int Nstride, int act, int nblk)
{
    const int bm   = blockIdx.x / nblk;
    const int bn   = blockIdx.x - bm * nblk;
    const int row0 = bm * 128 + (threadIdx.x >> 6) * 32;
    const int n0   = bn * 64;
    const int lane = threadIdx.x & 63;
    const int l15  = lane & 15;
    const int kg   = lane >> 4;

    f32x4 acc[2][4] = {};
    for (int k0 = 0; k0 < K; k0 += 32) {
        bf16x8 a0 = *(const bf16x8*)&Ab[(row0 + l15) * K + k0 + kg * 8];
        bf16x8 a1 = *(const bf16x8*)&Ab[(row0 + 16 + l15) * K + k0 + kg * 8];
        #pragma unroll
        for (int nt = 0; nt < 4; ++nt) {
            bf16x8 bfr = *(const bf16x8*)&Bt[(n0 + nt * 16 + l15) * K + k0 + kg * 8];
            acc[0][nt] = __builtin_amdgcn_mfma_f32_16x16x32_bf16(a0, bfr, acc[0][nt], 0, 0, 0);
            acc[1][nt] = __builtin_amdgcn_mfma_f32_16x16x32_bf16(a1, bfr, acc[1][nt], 0, 0, 0);
        }
    }
    #pragma unroll
    for (int m = 0; m < 2; ++m)
        #pragma unroll
        for (int nt = 0; nt < 4; ++nt) {
            int col = n0 + nt * 16 + l15;
            if (col < N) {
                float bv = bias[col];
                #pragma unroll
                for (int r = 0; r < 4; ++r) {
                    int row = row0 + m * 16 + kg * 4 + r;
                    float v = acc[m][nt][r] + bv;
                    if (act) v = tanhf(v);
                    outb[row * Nstride + col] = f2b(v);
                }
            }
        }
}

// ---------------------------------------------------------------------------
// Conv-weight prep (unchanged from r28/r29)
// ---------------------------------------------------------------------------
__global__ __launch_bounds__(256) void prep_weights_kernel(
    const float* __restrict__ c0_wq, const float* __restrict__ c0_wk,
    const float* __restrict__ c0_wv, const float* __restrict__ c0_we,
    const float* __restrict__ c0_weo,
    const float* __restrict__ c1_wq, const float* __restrict__ c1_wk,
    const float* __restrict__ c1_wv, const float* __restrict__ c1_we,
    const float* __restrict__ c1_weo,
    ushort_t* __restrict__ wb)
{
    int idx = blockIdx.x * 256 + threadIdx.x;
    if (idx < 40960) {
        int buf = idx / 5120, r = idx - buf * 5120;
        int n = r / 40, m = r - n * 40;
        const float* src; int K;
        switch (buf) {
            case 0: src = c0_wq; K = 13; break;
            case 1: src = c0_wk; K = 13; break;
            case 2: src = c0_wv; K = 13; break;
            case 3: src = c0_we; K = 5;  break;
            case 4: src = c1_wq; K = 32; break;
            case 5: src = c1_wk; K = 32; break;
            case 6: src = c1_wv; K = 32; break;
            default: src = c1_we; K = 32; break;
        }
        wb[idx] = (m < K) ? f2b(src[m * 128 + n]) : (ushort_t)0;
    } else if (idx < 47616) {
        int r2 = idx - 40960;
        int which = r2 / 3328, r = r2 - which * 3328;
        int c = r / 104, row = r - c * 104;
        float v = 0.f;
        if (which) {
            if (row < 96) v = c1_weo[row * 32 + c];
        } else {
            if (row < 13)                    v = c0_weo[row * 32 + c];
            else if (row >= 16 && row < 29)  v = c0_weo[(13 + row - 16) * 32 + c];
            else if (row >= 32 && row < 37)  v = c0_weo[(26 + row - 32) * 32 + c];
        }
        wb[idx] = f2b(v);
    }
}

// ---------------------------------------------------------------------------
// MLP prep (unchanged from r29)
// ---------------------------------------------------------------------------
__global__ __launch_bounds__(256) void prep_mlp_kernel(
    const float* __restrict__ w0, const float* __restrict__ w1,
    const float* __restrict__ w2, const float* __restrict__ we,
    const float* __restrict__ wn, const float* __restrict__ latent,
    ushort_t* __restrict__ bt, ushort_t* __restrict__ latb)
{
    int idx = blockIdx.x * 256 + threadIdx.x;
    if (idx < 16384) {
        int n = idx >> 7, k = idx & 127;
        bt[idx] = f2b(w0[k * 128 + n]);
    } else if (idx < 49152) {
        int r = idx - 16384, n = r >> 7, k = r & 127;
        bt[idx] = f2b(w1[k * 256 + n]);
    } else if (idx < 180224) {
        int r = idx - 49152, n = r >> 8, k = r & 255;
        bt[idx] = f2b(w2[k * 512 + n]);
    } else if (idx < 409600) {
        int r = idx - 180224, n = r >> 9, k = r & 511;
        bt[idx] = (n < 405) ? f2b(we[k * 405 + n]) : (ushort_t)0;
    } else if (idx < 475136) {
        int r = idx - 409600, n = r >> 9, k = r & 511;
        bt[idx] = (n < 117) ? f2b(wn[k * 117 + n]) : (ushort_t)0;
    } else if (idx < 999424) {
        int r = idx - 475136;
        latb[r] = f2b(latent[r]);
    }
}

// ---------------------------------------------------------------------------
// MFMA conv layer -- EXACT r29 form (scalar P2a/P2b/P3; measured 205 us,
// VGPR 48, no spills).  The r30 vectorized variant spilled at cap 64.
// ---------------------------------------------------------------------------
template <int XD, int ED2>
__device__ __forceinline__ void conv_layer(
    ushort_t* xsb, ushort_t* esb,
    const ushort_t* __restrict__ wq_p, const ushort_t* __restrict__ wk_p,
    const ushort_t* __restrict__ wv_p, const ushort_t* __restrict__ we_p,
    const ushort_t* __restrict__ weo_p,
    ushort_t* qb, ushort_t* kb, ushort_t* vb,
    ushort_t* ehb, float* en, float* xn, float* la, int tid)
{
    const int wv_  = tid >> 6;
    const int lane = tid & 63;
    const int l15  = lane & 15;
    const int kg   = lane >> 4;

    // P1 (merged): q,k (16 tasks) + v (8) + eh (48) = 72 wave-tasks
    for (int task = wv_; task < 72; task += 8) {
        if (task < 16) {
            int mat = task >> 3, nt = task & 7;
            bf16x8 a = *(const bf16x8*)&xsb[l15 * 40 + kg * 8];
            const ushort_t* wp = mat ? wk_p : wq_p;
            bf16x8 bf = *(const bf16x8*)&wp[(nt * 16 + l15) * 40 + kg * 8];
            f32x4 d = {0.f, 0.f, 0.f, 0.f};
            d = __builtin_amdgcn_mfma_f32_16x16x32_bf16(a, bf, d, 0, 0, 0);
            ushort_t* dst = mat ? kb : qb;
            #pragma unroll
            for (int r = 0; r < 4; ++r)
                dst[(kg * 4 + r) * 132 + nt * 16 + l15] = f2b(d[r]);
        } else if (task < 24) {
            int nt = task - 16;
            bf16x8 a = *(const bf16x8*)&xsb[l15 * 40 + kg * 8];
            bf16x8 bf = *(const bf16x8*)&wv_p[(nt * 16 + l15) * 40 + kg * 8];
            f32x4 d = {0.f, 0.f, 0.f, 0.f};
            d = __builtin_amdgcn_mfma_f32_16x16x32_bf16(a, bf, d, 0, 0, 0);
            #pragma unroll
            for (int r = 0; r < 4; ++r)
                vb[(kg * 4 + r) * 132 + nt * 16 + l15] = f2b(d[r]);
        } else {
            int t2 = task - 24, mt = t2 >> 3, nt = t2 & 7;
            bf16x8 a = *(const bf16x8*)&esb[(mt * 16 + l15) * 40 + kg * 8];
            bf16x8 bf = *(const bf16x8*)&we_p[(nt * 16 + l15) * 40 + kg * 8];
            f32x4 d = {0.f, 0.f, 0.f, 0.f};
            d = __builtin_amdgcn_mfma_f32_16x16x32_bf16(a, bf, d, 0, 0, 0);
            #pragma unroll
            for (int r = 0; r < 4; ++r)
                ehb[(mt * 16 + kg * 4 + r) * 132 + nt * 16 + l15] = f2b(d[r]);
        }
    }
    __syncthreads();

    // P2a: logits
    for (int idx = tid; idx < 324; idx += TPB) {
        int le = idx >> 2, h = idx & 3;
        int i = le / 9, j = le - i * 9;
        const ushort_t* qp = &qb[j * 132 + h * 32];
        const ushort_t* kp = &kb[i * 132 + h * 32];
        const ushort_t* ep = &ehb[le * 132 + h * 32];
        float acc = 0.f;
        #pragma unroll
        for (int d = 0; d < 32; ++d)
            acc = fmaf(b2f(qp[d]), b2f(kp[d]) + b2f(ep[d]), acc);
        la[idx] = acc * 0.17677669529663687f;
    }
    __syncthreads();

    // P2b: segment softmax
    for (int s = tid; s < 36; s += TPB) {
        int j = s >> 2, h = s & 3;
        float m = -1e30f;
        #pragma unroll
        for (int i = 0; i < 9; ++i) m = fmaxf(m, la[(i * 9 + j) * 4 + h]);
        float ex[9], sum = 0.f;
        #pragma unroll
        for (int i = 0; i < 9; ++i) { ex[i] = __expf(la[(i * 9 + j) * 4 + h] - m); sum += ex[i]; }
        float inv = 1.f / (sum + 1e-16f);
        #pragma unroll
        for (int i = 0; i < 9; ++i) la[(i * 9 + j) * 4 + h] = ex[i] * inv;
    }
    __syncthreads();

    // P3: aggregation -> xn (aliases qb)
    for (int idx = tid; idx < 288; idx += TPB) {
        int j = idx >> 5, d = idx & 31;
        float acc = 0.f;
        #pragma unroll
        for (int h = 0; h < 4; ++h)
            #pragma unroll
            for (int i = 0; i < 9; ++i) {
                int le = i * 9 + j;
                acc = fmaf(la[le * 4 + h],
                           b2f(vb[i * 132 + h * 32 + d]) + b2f(ehb[le * 132 + h * 32 + d]), acc);
            }
        xn[idx] = acc * 0.25f;
    }
    __syncthreads();

    // P4: edge-MLP, A-frags direct from xsb/esb
    const int KS = (XD == 13) ? 2 : 3;
    for (int task = wv_; task < 12; task += 8) {
        int mt = task >> 1, nt = task & 1;
        int le = mt * 16 + l15;
        int i = le / 9, j = le - i * 9;
        f32x4 d = {0.f, 0.f, 0.f, 0.f};
        #pragma unroll
        for (int ks = 0; ks < KS; ++ks) {
            bf16x8 a;
            if (XD == 13) {
                if (ks == 0)
                    a = (kg < 2) ? *(const bf16x8*)&xsb[i * 40 + kg * 8]
                                 : *(const bf16x8*)&xsb[j * 40 + (kg - 2) * 8];
                else
                    a = *(const bf16x8*)&esb[le * 40 + kg * 8];
            } else {
                a = (ks == 0) ? *(const bf16x8*)&xsb[i * 40 + kg * 8]
                  : (ks == 1) ? *(const bf16x8*)&xsb[j * 40 + kg * 8]
                              : *(const bf16x8*)&esb[le * 40 + kg * 8];
            }
            bf16x8 bf = *(const bf16x8*)&weo_p[(nt * 16 + l15) * 104 + ks * 32 + kg * 8];
            d = __builtin_amdgcn_mfma_f32_16x16x32_bf16(a, bf, d, 0, 0, 0);
        }
        #pragma unroll
        for (int r = 0; r < 4; ++r) {
            int row = mt * 16 + kg * 4 + r;
            if (row < 81) en[row * 32 + nt * 16 + l15] = d[r];
        }
    }
    __syncthreads();
}

// ---------------------------------------------------------------------------
// Fused GNN: r29 conv core + low-register epilogue upgrades (LDS-staged
// w_feat/w_eout transposes, shfl-LN, f32x4 e-leaky).  LDS ~50.5 KB.
// ---------------------------------------------------------------------------
__global__ __launch_bounds__(TPB, 4) void fused_gnn_kernel(
    const ushort_t* __restrict__ nlb,  // [B][120] bf16
    const ushort_t* __restrict__ elb,  // [B][408] bf16
    const ushort_t* __restrict__ wb,
    const float* __restrict__ ln0_g, const float* __restrict__ ln0_b,
    const float* __restrict__ ln1_g, const float* __restrict__ ln1_b,
    const float* __restrict__ w_feat, const float* __restrict__ w_eout,
    float* __restrict__ out)
{
    __shared__ __align__(16) ushort_t xsb[16 * 40];
    __shared__ __align__(16) ushort_t esb[96 * 40];
    __shared__ __align__(16) ushort_t qb[16 * 132];
    __shared__ __align__(16) ushort_t kb[16 * 132];
    __shared__ __align__(16) ushort_t vb[16 * 132];
    __shared__ __align__(16) ushort_t ehb[96 * 132];
    __shared__ __align__(16) float la[324];
    __shared__ __align__(16) float wfT[10 * 32];   // w_feat^T [c][kk]
    __shared__ __align__(16) float weT[5 * 32];    // w_eout^T [c][kk]

    float* en = (float*)ehb;
    float* xn = (float*)qb;

    const int b   = blockIdx.x;
    const int tid = threadIdx.x;

    for (int idx = tid; idx < 16 * 40; idx += TPB) xsb[idx] = 0;
    for (int idx = tid; idx < 96 * 40; idx += TPB) esb[idx] = 0;
    for (int idx = tid; idx < 320; idx += TPB) {
        int c = idx >> 5, kk = idx & 31;
        wfT[idx] = w_feat[kk * 10 + c];
    }
    for (int idx = tid; idx < 160; idx += TPB) {
        int c = idx >> 5, kk = idx & 31;
        weT[idx] = w_eout[kk * 5 + c];
    }
    __syncthreads();
    for (int idx = tid; idx < 117; idx += TPB) {
        int node = idx / 13, m = idx - node * 13;
        xsb[node * 40 + m] = nlb[b * 120 + idx];
    }
    for (int idx = tid; idx < 405; idx += TPB) {
        int le = idx / 5, c = idx - le * 5;
        int i = le / 9, j = le - i * 9;
        esb[le * 40 + c] = f2b(0.5f * (b2f(elb[b * 408 + c * 81 + i * 9 + j]) +
                                       b2f(elb[b * 408 + c * 81 + j * 9 + i])));
    }
    __syncthreads();

    for (int layer = 0; layer < 3; ++layer) {
        if (layer == 0)
            conv_layer<13, 5>(xsb, esb,
                              wb + 0, wb + 5120, wb + 10240, wb + 15360, wb + 40960,
                              qb, kb, vb, ehb, en, xn, la, tid);
        else
            conv_layer<32, 32>(xsb, esb,
                               wb + 20480, wb + 25600, wb + 30720, wb + 35840, wb + 44288,
                               qb, kb, vb, ehb, en, xn, la, tid);

        // P5 (layers 0,1): x = leaky(LN(xn)) via shfl; e = leaky(en) f32x4
        if (layer < 2) {
            const float* g  = (layer == 0) ? ln0_g : ln1_g;
            const float* be = (layer == 0) ? ln0_b : ln1_b;
            if (tid < 288) {
                int j = tid >> 5, c = tid & 31;
                float v = xn[tid];
                float s = v, q = v * v;
                #pragma unroll
                for (int m = 1; m <= 16; m <<= 1) {
                    s += __shfl_xor(s, m, 64);
                    q += __shfl_xor(q, m, 64);
                }
                float mu  = s * (1.f / 32.f);
                float var = q * (1.f / 32.f) - mu * mu;
                float val = (v - mu) / sqrtf(var + 1e-5f);
                val = val * g[c] + be[c];
                xsb[j * 40 + c] = f2b((val > 0.f) ? val : 0.01f * val);
            }
            for (int idx = tid; idx < 648; idx += TPB) {
                int le = idx >> 3, cg = (idx & 7) * 4;
                f32x4 v = *(const f32x4*)&en[le * 32 + cg];
                #pragma unroll
                for (int u = 0; u < 4; ++u) {
                    float x = v[u];
                    esb[le * 40 + cg + u] = f2b((x > 0.f) ? x : 0.01f * x);
                }
            }
            __syncthreads();
        }
    }

    float* out_x  = out;                       // [36864,10]
    float* out_e  = out + 368640;              // [294912,5]
    float* out_ei = out + 1843200;             // [2,294912]
    float* out_b  = out + 2433024;             // [36864]

    for (int idx = tid; idx < 90; idx += TPB) {
        int j = idx / 10, c = idx - j * 10;
        float acc = 0.f;
        #pragma unroll
        for (int kg2 = 0; kg2 < 8; ++kg2) {
            f32x4 xv = *(const f32x4*)&xn[j * 32 + kg2 * 4];
            f32x4 wv = *(const f32x4*)&wfT[c * 32 + kg2 * 4];
            #pragma unroll
            for (int u = 0; u < 4; ++u) acc = fmaf(xv[u], wv[u], acc);
        }
        out_x[(b * 9 + j) * 10 + c] = acc;
    }
    for (int idx = tid; idx < 360; idx += TPB) {
        int r = idx / 5, c = idx - r * 5;
        int i = r >> 3, jj = r & 7;
        int j = jj + (jj >= i ? 1 : 0);
        const float* row = &en[(i * 9 + j) * 32];
        float acc = 0.f;
        #pragma unroll
        for (int kg2 = 0; kg2 < 8; ++kg2) {
            f32x4 ev = *(const f32x4*)&row[kg2 * 4];
            f32x4 wv = *(const f32x4*)&weT[c * 32 + kg2 * 4];
            #pragma unroll
            for (int u = 0; u < 4; ++u) acc = fmaf(ev[u], wv[u], acc);
        }
        out_e[(b * 72 + r) * 5 + c] = acc;
    }
    for (int idx = tid; idx < 72; idx += TPB) {
        int i = idx >> 3, jj = idx & 7;
        int j = jj + (jj >= i ? 1 : 0);
        out_ei[b * 72 + idx]          = (float)(b * 9 + i);
        out_ei[294912 + b * 72 + idx] = (float)(b * 9 + j);
    }
    for (int idx = tid; idx < 9; idx += TPB)
        out_b[b * 9 + idx] = (float)b;
}

// ---------------------------------------------------------------------------
extern "C" void kernel_launch(void* const* d_in, const int* in_sizes, int n_in,
                              void* d_out, int out_size, void* d_ws, size_t ws_size,
                              hipStream_t stream)
{
    const float* latent  = (const float*)d_in[0];
    const float* w_mlp0  = (const float*)d_in[1];
    const float* b_mlp0  = (const float*)d_in[2];
    const float* w_mlp1  = (const float*)d_in[3];
    const float* b_mlp1  = (const float*)d_in[4];
    const float* w_mlp2  = (const float*)d_in[5];
    const float* b_mlp2  = (const float*)d_in[6];
    const float* w_edges = (const float*)d_in[7];
    const float* b_edges = (const float*)d_in[8];
    const float* w_nodes = (const float*)d_in[9];
    const float* b_nodes = (const float*)d_in[10];
    const float* c0_wq   = (const float*)d_in[11];
    const float* c0_wk   = (const float*)d_in[12];
    const float* c0_wv   = (const float*)d_in[13];
    const float* c0_we   = (const float*)d_in[14];
    const float* c0_weo  = (const float*)d_in[15];
    const float* c1_wq   = (const float*)d_in[16];
    const float* c1_wk   = (const float*)d_in[17];
    const float* c1_wv   = (const float*)d_in[18];
    const float* c1_we   = (const float*)d_in[19];
    const float* c1_weo  = (const float*)d_in[20];
    const float* ln0_g   = (const float*)d_in[21];
    const float* ln0_b   = (const float*)d_in[22];
    const float* ln1_g   = (const float*)d_in[23];
    const float* ln1_b   = (const float*)d_in[24];
    const float* w_feat  = (const float*)d_in[25];
    const float* w_eout  = (const float*)d_in[26];

    // Workspace (ushort offsets; all 16B-aligned) -- unchanged from r29
    ushort_t* wsu  = (ushort_t*)d_ws;
    ushort_t* wb   = wsu;
    ushort_t* bt   = wsu + 47616;
    ushort_t* latb = wsu + 522752;
    ushort_t* h0b  = wsu + 1047040;
    ushort_t* h1b  = wsu + 1571328;
    ushort_t* h2b  = wsu + 2619904;
    ushort_t* elb  = wsu + 4717056;
    ushort_t* nlb  = wsu + 6388224;

    float* out = (float*)d_out;

    prep_weights_kernel<<<187, 256, 0, stream>>>(
        c0_wq, c0_wk, c0_wv, c0_we, c0_weo,
        c1_wq, c1_wk, c1_wv, c1_we, c1_weo, wb);
    prep_mlp_kernel<<<3904, 256, 0, stream>>>(
        w_mlp0, w_mlp1, w_mlp2, w_edges, w_nodes, latent, bt, latb);

    gemm_mfma_kernel<<<32 * 2, 256, 0, stream>>>(latb, bt + 0,      b_mlp0, h0b, 128, 128, 128, 1, 2);
    gemm_mfma_kernel<<<32 * 4, 256, 0, stream>>>(h0b,  bt + 16384,  b_mlp1, h1b, 128, 256, 256, 1, 4);
    gemm_mfma_kernel<<<32 * 8, 256, 0, stream>>>(h1b,  bt + 49152,  b_mlp2, h2b, 256, 512, 512, 1, 8);
    gemm_mfma_kernel<<<32 * 7, 256, 0, stream>>>(h2b,  bt + 180224, b_edges, elb, 512, 405, 408, 0, 7);
    gemm_mfma_kernel<<<32 * 2, 256, 0, stream>>>(h2b,  bt + 409600, b_nodes, nlb, 512, 117, 120, 0, 2);

    fused_gnn_kernel<<<B_, TPB, 0, stream>>>(nlb, elb, wb,
        ln0_g, ln0_b, ln1_g, ln1_b, w_feat, w_eout, out);
}

// Round 32
// 243.110 us; speedup vs baseline: 1.1013x; 1.0248x over previous
//
#include <hip/hip_runtime.h>
#include <hip/hip_bf16.h>
#include <math.h>

#define B_    4096
#define V_    9
#define N_    (B_*V_)          // 36864 nodes
#define EK_   (B_*V_*(V_-1))   // 294912 kept edges
#define TPB   512

typedef unsigned short ushort_t;
typedef __attribute__((ext_vector_type(8))) short bf16x8;   // 8 bf16 (4 VGPRs)
typedef __attribute__((ext_vector_type(4))) float f32x4;    // 4 f32 / 16B chunk

__device__ __forceinline__ float b2f(ushort_t u) {
    union { unsigned int i; float f; } x; x.i = ((unsigned int)u) << 16; return x.f;
}
__device__ __forceinline__ ushort_t f2b(float f) {
    union { float f; unsigned int i; } x; x.f = f;
    unsigned int r = x.i + 0x7FFFu + ((x.i >> 16) & 1u);
    return (ushort_t)(r >> 16);
}

// ---------------------------------------------------------------------------
// MFMA GEMM for the MLP chain.  MT = 16-row frags per wave (MT=1: 64-row
// blocks -> 2x grid vs r29's 128-row, better CU coverage on latency-bound
// small-N dispatches).  Fragment layouts proven r21-r31.
// ---------------------------------------------------------------------------
template <int MT>
__global__ __launch_bounds__(256) void gemm_mfma_kernel(
    const ushort_t* __restrict__ Ab, const ushort_t* __restrict__ Bt,
    const float* __restrict__ bias, ushort_t* __restrict__ outb,
    int K, int N, int Nstride, int act, int nblk)
{
    const int bm   = blockIdx.x / nblk;
    const int bn   = blockIdx.x - bm * nblk;
    const int row0 = bm * (64 * MT) + (threadIdx.x >> 6) * (16 * MT);
    const int n0   = bn * 64;
    const int lane = threadIdx.x & 63;
    const int l15  = lane & 15;
    const int kg   = lane >> 4;

    f32x4 acc[MT][4] = {};
    for (int k0 = 0; k0 < K; k0 += 32) {
        bf16x8 a[MT];
        #pragma unroll
        for (int m = 0; m < MT; ++m)
            a[m] = *(const bf16x8*)&Ab[(row0 + m * 16 + l15) * K + k0 + kg * 8];
        #pragma unroll
        for (int nt = 0; nt < 4; ++nt) {
            bf16x8 bfr = *(const bf16x8*)&Bt[(n0 + nt * 16 + l15) * K + k0 + kg * 8];
            #pragma unroll
            for (int m = 0; m < MT; ++m)
                acc[m][nt] = __builtin_amdgcn_mfma_f32_16x16x32_bf16(a[m], bfr, acc[m][nt], 0, 0, 0);
        }
    }
    #pragma unroll
    for (int m = 0; m < MT; ++m)
        #pragma unroll
        for (int nt = 0; nt < 4; ++nt) {
            int col = n0 + nt * 16 + l15;
            if (col < N) {
                float bv = bias[col];
                #pragma unroll
                for (int r = 0; r < 4; ++r) {
                    int row = row0 + m * 16 + kg * 4 + r;
                    float v = acc[m][nt][r] + bv;
                    if (act) v = tanhf(v);
                    outb[row * Nstride + col] = f2b(v);
                }
            }
        }
}

// ---------------------------------------------------------------------------
// Merged prep: conv-weight images + MLP Bt images + latent bf16 (one launch).
// Index space: [0..999424) = MLP part (bt/latb), [999424..1047040) = conv wb.
// ---------------------------------------------------------------------------
__global__ __launch_bounds__(256) void prep_all_kernel(
    const float* __restrict__ w0, const float* __restrict__ w1,
    const float* __restrict__ w2, const float* __restrict__ we,
    const float* __restrict__ wn, const float* __restrict__ latent,
    const float* __restrict__ c0_wq, const float* __restrict__ c0_wk,
    const float* __restrict__ c0_wv, const float* __restrict__ c0_we,
    const float* __restrict__ c0_weo,
    const float* __restrict__ c1_wq, const float* __restrict__ c1_wk,
    const float* __restrict__ c1_wv, const float* __restrict__ c1_we,
    const float* __restrict__ c1_weo,
    ushort_t* __restrict__ bt, ushort_t* __restrict__ latb,
    ushort_t* __restrict__ wb)
{
    int idx = blockIdx.x * 256 + threadIdx.x;
    if (idx < 16384) {                       // L0 Bt: K=128, N=128
        int n = idx >> 7, k = idx & 127;
        bt[idx] = f2b(w0[k * 128 + n]);
    } else if (idx < 49152) {                // L1 Bt: K=128, N=256
        int r = idx - 16384, n = r >> 7, k = r & 127;
        bt[idx] = f2b(w1[k * 256 + n]);
    } else if (idx < 180224) {               // L2 Bt: K=256, N=512
        int r = idx - 49152, n = r >> 8, k = r & 255;
        bt[idx] = f2b(w2[k * 512 + n]);
    } else if (idx < 409600) {               // L3 Bt: K=512, N=405 (pad 448)
        int r = idx - 180224, n = r >> 9, k = r & 511;
        bt[idx] = (n < 405) ? f2b(we[k * 405 + n]) : (ushort_t)0;
    } else if (idx < 475136) {               // L4 Bt: K=512, N=117 (pad 128)
        int r = idx - 409600, n = r >> 9, k = r & 511;
        bt[idx] = (n < 117) ? f2b(wn[k * 117 + n]) : (ushort_t)0;
    } else if (idx < 999424) {               // latent f32 -> bf16
        int r = idx - 475136;
        latb[r] = f2b(latent[r]);
    } else if (idx < 1040384) {              // conv qkv/e images (8 x 5120)
        int widx = idx - 999424;
        int buf = widx / 5120, r = widx - buf * 5120;
        int n = r / 40, m = r - n * 40;
        const float* src; int K;
        switch (buf) {
            case 0: src = c0_wq; K = 13; break;
            case 1: src = c0_wk; K = 13; break;
            case 2: src = c0_wv; K = 13; break;
            case 3: src = c0_we; K = 5;  break;
            case 4: src = c1_wq; K = 32; break;
            case 5: src = c1_wk; K = 32; break;
            case 6: src = c1_wv; K = 32; break;
            default: src = c1_we; K = 32; break;
        }
        wb[widx] = (m < K) ? f2b(src[m * 128 + n]) : (ushort_t)0;
    } else if (idx < 1047040) {              // conv weo images (2 x 3328)
        int r2 = idx - 1040384;
        int which = r2 / 3328, r = r2 - which * 3328;
        int c = r / 104, row = r - c * 104;
        float v = 0.f;
        if (which) {
            if (row < 96) v = c1_weo[row * 32 + c];
        } else {
            if (row < 13)                    v = c0_weo[row * 32 + c];
            else if (row >= 16 && row < 29)  v = c0_weo[(13 + row - 16) * 32 + c];
            else if (row >= 32 && row < 37)  v = c0_weo[(26 + row - 32) * 32 + c];
        }
        wb[40960 + r2] = f2b(v);
    }
}

// ---------------------------------------------------------------------------
// MFMA conv layer -- EXACT r29/r31 form (measured 191 us, VGPR 48, no spills)
// ---------------------------------------------------------------------------
template <int XD, int ED2>
__device__ __forceinline__ void conv_layer(
    ushort_t* xsb, ushort_t* esb,
    const ushort_t* __restrict__ wq_p, const ushort_t* __restrict__ wk_p,
    const ushort_t* __restrict__ wv_p, const ushort_t* __restrict__ we_p,
    const ushort_t* __restrict__ weo_p,
    ushort_t* qb, ushort_t* kb, ushort_t* vb,
    ushort_t* ehb, float* en, float* xn, float* la, int tid)
{
    const int wv_  = tid >> 6;
    const int lane = tid & 63;
    const int l15  = lane & 15;
    const int kg   = lane >> 4;

    // P1 (merged): q,k (16 tasks) + v (8) + eh (48) = 72 wave-tasks
    for (int task = wv_; task < 72; task += 8) {
        if (task < 16) {
            int mat = task >> 3, nt = task & 7;
            bf16x8 a = *(const bf16x8*)&xsb[l15 * 40 + kg * 8];
            const ushort_t* wp = mat ? wk_p : wq_p;
            bf16x8 bf = *(const bf16x8*)&wp[(nt * 16 + l15) * 40 + kg * 8];
            f32x4 d = {0.f, 0.f, 0.f, 0.f};
            d = __builtin_amdgcn_mfma_f32_16x16x32_bf16(a, bf, d, 0, 0, 0);
            ushort_t* dst = mat ? kb : qb;
            #pragma unroll
            for (int r = 0; r < 4; ++r)
                dst[(kg * 4 + r) * 132 + nt * 16 + l15] = f2b(d[r]);
        } else if (task < 24) {
            int nt = task - 16;
            bf16x8 a = *(const bf16x8*)&xsb[l15 * 40 + kg * 8];
            bf16x8 bf = *(const bf16x8*)&wv_p[(nt * 16 + l15) * 40 + kg * 8];
            f32x4 d = {0.f, 0.f, 0.f, 0.f};
            d = __builtin_amdgcn_mfma_f32_16x16x32_bf16(a, bf, d, 0, 0, 0);
            #pragma unroll
            for (int r = 0; r < 4; ++r)
                vb[(kg * 4 + r) * 132 + nt * 16 + l15] = f2b(d[r]);
        } else {
            int t2 = task - 24, mt = t2 >> 3, nt = t2 & 7;
            bf16x8 a = *(const bf16x8*)&esb[(mt * 16 + l15) * 40 + kg * 8];
            bf16x8 bf = *(const bf16x8*)&we_p[(nt * 16 + l15) * 40 + kg * 8];
            f32x4 d = {0.f, 0.f, 0.f, 0.f};
            d = __builtin_amdgcn_mfma_f32_16x16x32_bf16(a, bf, d, 0, 0, 0);
            #pragma unroll
            for (int r = 0; r < 4; ++r)
                ehb[(mt * 16 + kg * 4 + r) * 132 + nt * 16 + l15] = f2b(d[r]);
        }
    }
    __syncthreads();

    // P2a: logits
    for (int idx = tid; idx < 324; idx += TPB) {
        int le = idx >> 2, h = idx & 3;
        int i = le / 9, j = le - i * 9;
        const ushort_t* qp = &qb[j * 132 + h * 32];
        const ushort_t* kp = &kb[i * 132 + h * 32];
        const ushort_t* ep = &ehb[le * 132 + h * 32];
        float acc = 0.f;
        #pragma unroll
        for (int d = 0; d < 32; ++d)
            acc = fmaf(b2f(qp[d]), b2f(kp[d]) + b2f(ep[d]), acc);
        la[idx] = acc * 0.17677669529663687f;
    }
    __syncthreads();

    // P2b: segment softmax
    for (int s = tid; s < 36; s += TPB) {
        int j = s >> 2, h = s & 3;
        float m = -1e30f;
        #pragma unroll
        for (int i = 0; i < 9; ++i) m = fmaxf(m, la[(i * 9 + j) * 4 + h]);
        float ex[9], sum = 0.f;
        #pragma unroll
        for (int i = 0; i < 9; ++i) { ex[i] = __expf(la[(i * 9 + j) * 4 + h] - m); sum += ex[i]; }
        float inv = 1.f / (sum + 1e-16f);
        #pragma unroll
        for (int i = 0; i < 9; ++i) la[(i * 9 + j) * 4 + h] = ex[i] * inv;
    }
    __syncthreads();

    // P3: aggregation -> xn (aliases qb)
    for (int idx = tid; idx < 288; idx += TPB) {
        int j = idx >> 5, d = idx & 31;
        float acc = 0.f;
        #pragma unroll
        for (int h = 0; h < 4; ++h)
            #pragma unroll
            for (int i = 0; i < 9; ++i) {
                int le = i * 9 + j;
                acc = fmaf(la[le * 4 + h],
                           b2f(vb[i * 132 + h * 32 + d]) + b2f(ehb[le * 132 + h * 32 + d]), acc);
            }
        xn[idx] = acc * 0.25f;
    }
    __syncthreads();

    // P4: edge-MLP, A-frags direct from xsb/esb
    const int KS = (XD == 13) ? 2 : 3;
    for (int task = wv_; task < 12; task += 8) {
        int mt = task >> 1, nt = task & 1;
        int le = mt * 16 + l15;
        int i = le / 9, j = le - i * 9;
        f32x4 d = {0.f, 0.f, 0.f, 0.f};
        #pragma unroll
        for (int ks = 0; ks < KS; ++ks) {
            bf16x8 a;
            if (XD == 13) {
                if (ks == 0)
                    a = (kg < 2) ? *(const bf16x8*)&xsb[i * 40 + kg * 8]
                                 : *(const bf16x8*)&xsb[j * 40 + (kg - 2) * 8];
                else
                    a = *(const bf16x8*)&esb[le * 40 + kg * 8];
            } else {
                a = (ks == 0) ? *(const bf16x8*)&xsb[i * 40 + kg * 8]
                  : (ks == 1) ? *(const bf16x8*)&xsb[j * 40 + kg * 8]
                              : *(const bf16x8*)&esb[le * 40 + kg * 8];
            }
            bf16x8 bf = *(const bf16x8*)&weo_p[(nt * 16 + l15) * 104 + ks * 32 + kg * 8];
            d = __builtin_amdgcn_mfma_f32_16x16x32_bf16(a, bf, d, 0, 0, 0);
        }
        #pragma unroll
        for (int r = 0; r < 4; ++r) {
            int row = mt * 16 + kg * 4 + r;
            if (row < 81) en[row * 32 + nt * 16 + l15] = d[r];
        }
    }
    __syncthreads();
}

// ---------------------------------------------------------------------------
// Fused GNN (byte-identical to measured r31: 191 us)
// ---------------------------------------------------------------------------
__global__ __launch_bounds__(TPB, 4) void fused_gnn_kernel(
    const ushort_t* __restrict__ nlb,  // [B][120] bf16
    const ushort_t* __restrict__ elb,  // [B][408] bf16
    const ushort_t* __restrict__ wb,
    const float* __restrict__ ln0_g, const float* __restrict__ ln0_b,
    const float* __restrict__ ln1_g, const float* __restrict__ ln1_b,
    const float* __restrict__ w_feat, const float* __restrict__ w_eout,
    float* __restrict__ out)
{
    __shared__ __align__(16) ushort_t xsb[16 * 40];
    __shared__ __align__(16) ushort_t esb[96 * 40];
    __shared__ __align__(16) ushort_t qb[16 * 132];
    __shared__ __align__(16) ushort_t kb[16 * 132];
    __shared__ __align__(16) ushort_t vb[16 * 132];
    __shared__ __align__(16) ushort_t ehb[96 * 132];
    __shared__ __align__(16) float la[324];
    __shared__ __align__(16) float wfT[10 * 32];
    __shared__ __align__(16) float weT[5 * 32];

    float* en = (float*)ehb;
    float* xn = (float*)qb;

    const int b   = blockIdx.x;
    const int tid = threadIdx.x;

    for (int idx = tid; idx < 16 * 40; idx += TPB) xsb[idx] = 0;
    for (int idx = tid; idx < 96 * 40; idx += TPB) esb[idx] = 0;
    for (int idx = tid; idx < 320; idx += TPB) {
        int c = idx >> 5, kk = idx & 31;
        wfT[idx] = w_feat[kk * 10 + c];
    }
    for (int idx = tid; idx < 160; idx += TPB) {
        int c = idx >> 5, kk = idx & 31;
        weT[idx] = w_eout[kk * 5 + c];
    }
    __syncthreads();
    for (int idx = tid; idx < 117; idx += TPB) {
        int node = idx / 13, m = idx - node * 13;
        xsb[node * 40 + m] = nlb[b * 120 + idx];
    }
    for (int idx = tid; idx < 405; idx += TPB) {
        int le = idx / 5, c = idx - le * 5;
        int i = le / 9, j = le - i * 9;
        esb[le * 40 + c] = f2b(0.5f * (b2f(elb[b * 408 + c * 81 + i * 9 + j]) +
                                       b2f(elb[b * 408 + c * 81 + j * 9 + i])));
    }
    __syncthreads();

    for (int layer = 0; layer < 3; ++layer) {
        if (layer == 0)
            conv_layer<13, 5>(xsb, esb,
                              wb + 0, wb + 5120, wb + 10240, wb + 15360, wb + 40960,
                              qb, kb, vb, ehb, en, xn, la, tid);
        else
            conv_layer<32, 32>(xsb, esb,
                               wb + 20480, wb + 25600, wb + 30720, wb + 35840, wb + 44288,
                               qb, kb, vb, ehb, en, xn, la, tid);

        if (layer < 2) {
            const float* g  = (layer == 0) ? ln0_g : ln1_g;
            const float* be = (layer == 0) ? ln0_b : ln1_b;
            if (tid < 288) {
                int j = tid >> 5, c = tid & 31;
                float v = xn[tid];
                float s = v, q = v * v;
                #pragma unroll
                for (int m = 1; m <= 16; m <<= 1) {
                    s += __shfl_xor(s, m, 64);
                    q += __shfl_xor(q, m, 64);
                }
                float mu  = s * (1.f / 32.f);
                float var = q * (1.f / 32.f) - mu * mu;
                float val = (v - mu) / sqrtf(var + 1e-5f);
                val = val * g[c] + be[c];
                xsb[j * 40 + c] = f2b((val > 0.f) ? val : 0.01f * val);
            }
            for (int idx = tid; idx < 648; idx += TPB) {
                int le = idx >> 3, cg = (idx & 7) * 4;
                f32x4 v = *(const f32x4*)&en[le * 32 + cg];
                #pragma unroll
                for (int u = 0; u < 4; ++u) {
                    float x = v[u];
                    esb[le * 40 + cg + u] = f2b((x > 0.f) ? x : 0.01f * x);
                }
            }
            __syncthreads();
        }
    }

    float* out_x  = out;                       // [36864,10]
    float* out_e  = out + 368640;              // [294912,5]
    float* out_ei = out + 1843200;             // [2,294912]
    float* out_b  = out + 2433024;             // [36864]

    for (int idx = tid; idx < 90; idx += TPB) {
        int j = idx / 10, c = idx - j * 10;
        float acc = 0.f;
        #pragma unroll
        for (int kg2 = 0; kg2 < 8; ++kg2) {
            f32x4 xv = *(const f32x4*)&xn[j * 32 + kg2 * 4];
            f32x4 wv = *(const f32x4*)&wfT[c * 32 + kg2 * 4];
            #pragma unroll
            for (int u = 0; u < 4; ++u) acc = fmaf(xv[u], wv[u], acc);
        }
        out_x[(b * 9 + j) * 10 + c] = acc;
    }
    for (int idx = tid; idx < 360; idx += TPB) {
        int r = idx / 5, c = idx - r * 5;
        int i = r >> 3, jj = r & 7;
        int j = jj + (jj >= i ? 1 : 0);
        const float* row = &en[(i * 9 + j) * 32];
        float acc = 0.f;
        #pragma unroll
        for (int kg2 = 0; kg2 < 8; ++kg2) {
            f32x4 ev = *(const f32x4*)&row[kg2 * 4];
            f32x4 wv = *(const f32x4*)&weT[c * 32 + kg2 * 4];
            #pragma unroll
            for (int u = 0; u < 4; ++u) acc = fmaf(ev[u], wv[u], acc);
        }
        out_e[(b * 72 + r) * 5 + c] = acc;
    }
    for (int idx = tid; idx < 72; idx += TPB) {
        int i = idx >> 3, jj = idx & 7;
        int j = jj + (jj >= i ? 1 : 0);
        out_ei[b * 72 + idx]          = (float)(b * 9 + i);
        out_ei[294912 + b * 72 + idx] = (float)(b * 9 + j);
    }
    for (int idx = tid; idx < 9; idx += TPB)
        out_b[b * 9 + idx] = (float)b;
}

// ---------------------------------------------------------------------------
extern "C" void kernel_launch(void* const* d_in, const int* in_sizes, int n_in,
                              void* d_out, int out_size, void* d_ws, size_t ws_size,
                              hipStream_t stream)
{
    const float* latent  = (const float*)d_in[0];
    const float* w_mlp0  = (const float*)d_in[1];
    const float* b_mlp0  = (const float*)d_in[2];
    const float* w_mlp1  = (const float*)d_in[3];
    const float* b_mlp1  = (const float*)d_in[4];
    const float* w_mlp2  = (const float*)d_in[5];
    const float* b_mlp2  = (const float*)d_in[6];
    const float* w_edges = (const float*)d_in[7];
    const float* b_edges = (const float*)d_in[8];
    const float* w_nodes = (const float*)d_in[9];
    const float* b_nodes = (const float*)d_in[10];
    const float* c0_wq   = (const float*)d_in[11];
    const float* c0_wk   = (const float*)d_in[12];
    const float* c0_wv   = (const float*)d_in[13];
    const float* c0_we   = (const float*)d_in[14];
    const float* c0_weo  = (const float*)d_in[15];
    const float* c1_wq   = (const float*)d_in[16];
    const float* c1_wk   = (const float*)d_in[17];
    const float* c1_wv   = (const float*)d_in[18];
    const float* c1_we   = (const float*)d_in[19];
    const float* c1_weo  = (const float*)d_in[20];
    const float* ln0_g   = (const float*)d_in[21];
    const float* ln0_b   = (const float*)d_in[22];
    const float* ln1_g   = (const float*)d_in[23];
    const float* ln1_b   = (const float*)d_in[24];
    const float* w_feat  = (const float*)d_in[25];
    const float* w_eout  = (const float*)d_in[26];

    // Workspace (ushort offsets; all 16B-aligned) -- unchanged from r29/r31
    ushort_t* wsu  = (ushort_t*)d_ws;
    ushort_t* wb   = wsu;
    ushort_t* bt   = wsu + 47616;
    ushort_t* latb = wsu + 522752;
    ushort_t* h0b  = wsu + 1047040;
    ushort_t* h1b  = wsu + 1571328;
    ushort_t* h2b  = wsu + 2619904;
    ushort_t* elb  = wsu + 4717056;
    ushort_t* nlb  = wsu + 6388224;

    float* out = (float*)d_out;

    prep_all_kernel<<<4090, 256, 0, stream>>>(
        w_mlp0, w_mlp1, w_mlp2, w_edges, w_nodes, latent,
        c0_wq, c0_wk, c0_wv, c0_we, c0_weo,
        c1_wq, c1_wk, c1_wv, c1_we, c1_weo,
        bt, latb, wb);

    // MLP chain on MFMA, 64-row blocks (MT=1): grids 128..512
    gemm_mfma_kernel<1><<<64 * 2, 256, 0, stream>>>(latb, bt + 0,      b_mlp0, h0b, 128, 128, 128, 1, 2);
    gemm_mfma_kernel<1><<<64 * 4, 256, 0, stream>>>(h0b,  bt + 16384,  b_mlp1, h1b, 128, 256, 256, 1, 4);
    gemm_mfma_kernel<1><<<64 * 8, 256, 0, stream>>>(h1b,  bt + 49152,  b_mlp2, h2b, 256, 512, 512, 1, 8);
    gemm_mfma_kernel<1><<<64 * 7, 256, 0, stream>>>(h2b,  bt + 180224, b_edges, elb, 512, 405, 408, 0, 7);
    gemm_mfma_kernel<1><<<64 * 2, 256, 0, stream>>>(h2b,  bt + 409600, b_nodes, nlb, 512, 117, 120, 0, 2);

    fused_gnn_kernel<<<B_, TPB, 0, stream>>>(nlb, elb, wb,
        ln0_g, ln0_b, ln1_g, ln1_b, w_feat, w_eout, out);
}

// Round 33
// 239.911 us; speedup vs baseline: 1.1159x; 1.0133x over previous
//
#include <hip/hip_runtime.h>
#include <hip/hip_bf16.h>
#include <math.h>

#define B_    4096
#define V_    9
#define N_    (B_*V_)          // 36864 nodes
#define EK_   (B_*V_*(V_-1))   // 294912 kept edges
#define TPB   512

typedef unsigned short ushort_t;
typedef __attribute__((ext_vector_type(8))) short bf16x8;   // 8 bf16 (4 VGPRs)
typedef __attribute__((ext_vector_type(4))) float f32x4;    // 4 f32 / 16B chunk

__device__ __forceinline__ float b2f(ushort_t u) {
    union { unsigned int i; float f; } x; x.i = ((unsigned int)u) << 16; return x.f;
}
__device__ __forceinline__ ushort_t f2b(float f) {
    union { float f; unsigned int i; } x; x.f = f;
    unsigned int r = x.i + 0x7FFFu + ((x.i >> 16) & 1u);
    return (ushort_t)(r >> 16);
}

// ---------------------------------------------------------------------------
// MFMA GEMM for the MLP chain (MT=1: 64-row blocks; measured r32)
// ---------------------------------------------------------------------------
template <int MT>
__global__ __launch_bounds__(256) void gemm_mfma_kernel(
    const ushort_t* __restrict__ Ab, const ushort_t* __restrict__ Bt,
    const float* __restrict__ bias, ushort_t* __restrict__ outb,
    int K, int N, int Nstride, int act, int nblk)
{
    const int bm   = blockIdx.x / nblk;
    const int bn   = blockIdx.x - bm * nblk;
    const int row0 = bm * (64 * MT) + (threadIdx.x >> 6) * (16 * MT);
    const int n0   = bn * 64;
    const int lane = threadIdx.x & 63;
    const int l15  = lane & 15;
    const int kg   = lane >> 4;

    f32x4 acc[MT][4] = {};
    for (int k0 = 0; k0 < K; k0 += 32) {
        bf16x8 a[MT];
        #pragma unroll
        for (int m = 0; m < MT; ++m)
            a[m] = *(const bf16x8*)&Ab[(row0 + m * 16 + l15) * K + k0 + kg * 8];
        #pragma unroll
        for (int nt = 0; nt < 4; ++nt) {
            bf16x8 bfr = *(const bf16x8*)&Bt[(n0 + nt * 16 + l15) * K + k0 + kg * 8];
            #pragma unroll
            for (int m = 0; m < MT; ++m)
                acc[m][nt] = __builtin_amdgcn_mfma_f32_16x16x32_bf16(a[m], bfr, acc[m][nt], 0, 0, 0);
        }
    }
    #pragma unroll
    for (int m = 0; m < MT; ++m)
        #pragma unroll
        for (int nt = 0; nt < 4; ++nt) {
            int col = n0 + nt * 16 + l15;
            if (col < N) {
                float bv = bias[col];
                #pragma unroll
                for (int r = 0; r < 4; ++r) {
                    int row = row0 + m * 16 + kg * 4 + r;
                    float v = acc[m][nt][r] + bv;
                    if (act) v = tanhf(v);
                    outb[row * Nstride + col] = f2b(v);
                }
            }
        }
}

// ---------------------------------------------------------------------------
// Dual GEMM: L3 (edges, blocks 0..447) + L4 (nodes, blocks 448..575) in ONE
// launch -- both consume h2b (K=512, act=0), independent outputs.
// ---------------------------------------------------------------------------
__global__ __launch_bounds__(256) void gemm_dual_kernel(
    const ushort_t* __restrict__ Ab,
    const ushort_t* __restrict__ bt3, const ushort_t* __restrict__ bt4,
    const float* __restrict__ b_edges, const float* __restrict__ b_nodes,
    ushort_t* __restrict__ elb, ushort_t* __restrict__ nlb)
{
    const bool second = (blockIdx.x >= 448);
    const ushort_t* Bt   = second ? bt4 : bt3;
    const float* bias    = second ? b_nodes : b_edges;
    ushort_t* outb       = second ? nlb : elb;
    const int N          = second ? 117 : 405;
    const int Nstride    = second ? 120 : 408;
    const int nblk       = second ? 2 : 7;
    const int bid        = second ? (blockIdx.x - 448) : blockIdx.x;

    const int bm   = bid / nblk;
    const int bn   = bid - bm * nblk;
    const int row0 = bm * 64 + (threadIdx.x >> 6) * 16;
    const int n0   = bn * 64;
    const int lane = threadIdx.x & 63;
    const int l15  = lane & 15;
    const int kg   = lane >> 4;

    f32x4 acc[4] = {};
    for (int k0 = 0; k0 < 512; k0 += 32) {
        bf16x8 a = *(const bf16x8*)&Ab[(row0 + l15) * 512 + k0 + kg * 8];
        #pragma unroll
        for (int nt = 0; nt < 4; ++nt) {
            bf16x8 bfr = *(const bf16x8*)&Bt[(n0 + nt * 16 + l15) * 512 + k0 + kg * 8];
            acc[nt] = __builtin_amdgcn_mfma_f32_16x16x32_bf16(a, bfr, acc[nt], 0, 0, 0);
        }
    }
    #pragma unroll
    for (int nt = 0; nt < 4; ++nt) {
        int col = n0 + nt * 16 + l15;
        if (col < N) {
            float bv = bias[col];
            #pragma unroll
            for (int r = 0; r < 4; ++r) {
                int row = row0 + kg * 4 + r;
                outb[row * Nstride + col] = f2b(acc[nt][r] + bv);
            }
        }
    }
}

// ---------------------------------------------------------------------------
// Merged prep: conv-weight images + MLP Bt images + latent bf16 (one launch)
// ---------------------------------------------------------------------------
__global__ __launch_bounds__(256) void prep_all_kernel(
    const float* __restrict__ w0, const float* __restrict__ w1,
    const float* __restrict__ w2, const float* __restrict__ we,
    const float* __restrict__ wn, const float* __restrict__ latent,
    const float* __restrict__ c0_wq, const float* __restrict__ c0_wk,
    const float* __restrict__ c0_wv, const float* __restrict__ c0_we,
    const float* __restrict__ c0_weo,
    const float* __restrict__ c1_wq, const float* __restrict__ c1_wk,
    const float* __restrict__ c1_wv, const float* __restrict__ c1_we,
    const float* __restrict__ c1_weo,
    ushort_t* __restrict__ bt, ushort_t* __restrict__ latb,
    ushort_t* __restrict__ wb)
{
    int idx = blockIdx.x * 256 + threadIdx.x;
    if (idx < 16384) {                       // L0 Bt: K=128, N=128
        int n = idx >> 7, k = idx & 127;
        bt[idx] = f2b(w0[k * 128 + n]);
    } else if (idx < 49152) {                // L1 Bt: K=128, N=256
        int r = idx - 16384, n = r >> 7, k = r & 127;
        bt[idx] = f2b(w1[k * 256 + n]);
    } else if (idx < 180224) {               // L2 Bt: K=256, N=512
        int r = idx - 49152, n = r >> 8, k = r & 255;
        bt[idx] = f2b(w2[k * 512 + n]);
    } else if (idx < 409600) {               // L3 Bt: K=512, N=405 (pad 448)
        int r = idx - 180224, n = r >> 9, k = r & 511;
        bt[idx] = (n < 405) ? f2b(we[k * 405 + n]) : (ushort_t)0;
    } else if (idx < 475136) {               // L4 Bt: K=512, N=117 (pad 128)
        int r = idx - 409600, n = r >> 9, k = r & 511;
        bt[idx] = (n < 117) ? f2b(wn[k * 117 + n]) : (ushort_t)0;
    } else if (idx < 999424) {               // latent f32 -> bf16
        int r = idx - 475136;
        latb[r] = f2b(latent[r]);
    } else if (idx < 1040384) {              // conv qkv/e images (8 x 5120)
        int widx = idx - 999424;
        int buf = widx / 5120, r = widx - buf * 5120;
        int n = r / 40, m = r - n * 40;
        const float* src; int K;
        switch (buf) {
            case 0: src = c0_wq; K = 13; break;
            case 1: src = c0_wk; K = 13; break;
            case 2: src = c0_wv; K = 13; break;
            case 3: src = c0_we; K = 5;  break;
            case 4: src = c1_wq; K = 32; break;
            case 5: src = c1_wk; K = 32; break;
            case 6: src = c1_wv; K = 32; break;
            default: src = c1_we; K = 32; break;
        }
        wb[widx] = (m < K) ? f2b(src[m * 128 + n]) : (ushort_t)0;
    } else if (idx < 1047040) {              // conv weo images (2 x 3328)
        int r2 = idx - 1040384;
        int which = r2 / 3328, r = r2 - which * 3328;
        int c = r / 104, row = r - c * 104;
        float v = 0.f;
        if (which) {
            if (row < 96) v = c1_weo[row * 32 + c];
        } else {
            if (row < 13)                    v = c0_weo[row * 32 + c];
            else if (row >= 16 && row < 29)  v = c0_weo[(13 + row - 16) * 32 + c];
            else if (row >= 32 && row < 37)  v = c0_weo[(26 + row - 32) * 32 + c];
        }
        wb[40960 + r2] = f2b(v);
    }
}

// ---------------------------------------------------------------------------
// MFMA conv layer -- EXACT r29/r31/r32 form (measured 191 us, VGPR 48)
// ---------------------------------------------------------------------------
template <int XD, int ED2>
__device__ __forceinline__ void conv_layer(
    ushort_t* xsb, ushort_t* esb,
    const ushort_t* __restrict__ wq_p, const ushort_t* __restrict__ wk_p,
    const ushort_t* __restrict__ wv_p, const ushort_t* __restrict__ we_p,
    const ushort_t* __restrict__ weo_p,
    ushort_t* qb, ushort_t* kb, ushort_t* vb,
    ushort_t* ehb, float* en, float* xn, float* la, int tid)
{
    const int wv_  = tid >> 6;
    const int lane = tid & 63;
    const int l15  = lane & 15;
    const int kg   = lane >> 4;

    // P1 (merged): q,k (16 tasks) + v (8) + eh (48) = 72 wave-tasks
    for (int task = wv_; task < 72; task += 8) {
        if (task < 16) {
            int mat = task >> 3, nt = task & 7;
            bf16x8 a = *(const bf16x8*)&xsb[l15 * 40 + kg * 8];
            const ushort_t* wp = mat ? wk_p : wq_p;
            bf16x8 bf = *(const bf16x8*)&wp[(nt * 16 + l15) * 40 + kg * 8];
            f32x4 d = {0.f, 0.f, 0.f, 0.f};
            d = __builtin_amdgcn_mfma_f32_16x16x32_bf16(a, bf, d, 0, 0, 0);
            ushort_t* dst = mat ? kb : qb;
            #pragma unroll
            for (int r = 0; r < 4; ++r)
                dst[(kg * 4 + r) * 132 + nt * 16 + l15] = f2b(d[r]);
        } else if (task < 24) {
            int nt = task - 16;
            bf16x8 a = *(const bf16x8*)&xsb[l15 * 40 + kg * 8];
            bf16x8 bf = *(const bf16x8*)&wv_p[(nt * 16 + l15) * 40 + kg * 8];
            f32x4 d = {0.f, 0.f, 0.f, 0.f};
            d = __builtin_amdgcn_mfma_f32_16x16x32_bf16(a, bf, d, 0, 0, 0);
            #pragma unroll
            for (int r = 0; r < 4; ++r)
                vb[(kg * 4 + r) * 132 + nt * 16 + l15] = f2b(d[r]);
        } else {
            int t2 = task - 24, mt = t2 >> 3, nt = t2 & 7;
            bf16x8 a = *(const bf16x8*)&esb[(mt * 16 + l15) * 40 + kg * 8];
            bf16x8 bf = *(const bf16x8*)&we_p[(nt * 16 + l15) * 40 + kg * 8];
            f32x4 d = {0.f, 0.f, 0.f, 0.f};
            d = __builtin_amdgcn_mfma_f32_16x16x32_bf16(a, bf, d, 0, 0, 0);
            #pragma unroll
            for (int r = 0; r < 4; ++r)
                ehb[(mt * 16 + kg * 4 + r) * 132 + nt * 16 + l15] = f2b(d[r]);
        }
    }
    __syncthreads();

    // P2a: logits
    for (int idx = tid; idx < 324; idx += TPB) {
        int le = idx >> 2, h = idx & 3;
        int i = le / 9, j = le - i * 9;
        const ushort_t* qp = &qb[j * 132 + h * 32];
        const ushort_t* kp = &kb[i * 132 + h * 32];
        const ushort_t* ep = &ehb[le * 132 + h * 32];
        float acc = 0.f;
        #pragma unroll
        for (int d = 0; d < 32; ++d)
            acc = fmaf(b2f(qp[d]), b2f(kp[d]) + b2f(ep[d]), acc);
        la[idx] = acc * 0.17677669529663687f;
    }
    __syncthreads();

    // P2b: segment softmax
    for (int s = tid; s < 36; s += TPB) {
        int j = s >> 2, h = s & 3;
        float m = -1e30f;
        #pragma unroll
        for (int i = 0; i < 9; ++i) m = fmaxf(m, la[(i * 9 + j) * 4 + h]);
        float ex[9], sum = 0.f;
        #pragma unroll
        for (int i = 0; i < 9; ++i) { ex[i] = __expf(la[(i * 9 + j) * 4 + h] - m); sum += ex[i]; }
        float inv = 1.f / (sum + 1e-16f);
        #pragma unroll
        for (int i = 0; i < 9; ++i) la[(i * 9 + j) * 4 + h] = ex[i] * inv;
    }
    __syncthreads();

    // P3: aggregation -> xn (aliases qb)
    for (int idx = tid; idx < 288; idx += TPB) {
        int j = idx >> 5, d = idx & 31;
        float acc = 0.f;
        #pragma unroll
        for (int h = 0; h < 4; ++h)
            #pragma unroll
            for (int i = 0; i < 9; ++i) {
                int le = i * 9 + j;
                acc = fmaf(la[le * 4 + h],
                           b2f(vb[i * 132 + h * 32 + d]) + b2f(ehb[le * 132 + h * 32 + d]), acc);
            }
        xn[idx] = acc * 0.25f;
    }
    __syncthreads();

    // P4: edge-MLP, A-frags direct from xsb/esb
    const int KS = (XD == 13) ? 2 : 3;
    for (int task = wv_; task < 12; task += 8) {
        int mt = task >> 1, nt = task & 1;
        int le = mt * 16 + l15;
        int i = le / 9, j = le - i * 9;
        f32x4 d = {0.f, 0.f, 0.f, 0.f};
        #pragma unroll
        for (int ks = 0; ks < KS; ++ks) {
            bf16x8 a;
            if (XD == 13) {
                if (ks == 0)
                    a = (kg < 2) ? *(const bf16x8*)&xsb[i * 40 + kg * 8]
                                 : *(const bf16x8*)&xsb[j * 40 + (kg - 2) * 8];
                else
                    a = *(const bf16x8*)&esb[le * 40 + kg * 8];
            } else {
                a = (ks == 0) ? *(const bf16x8*)&xsb[i * 40 + kg * 8]
                  : (ks == 1) ? *(const bf16x8*)&xsb[j * 40 + kg * 8]
                              : *(const bf16x8*)&esb[le * 40 + kg * 8];
            }
            bf16x8 bf = *(const bf16x8*)&weo_p[(nt * 16 + l15) * 104 + ks * 32 + kg * 8];
            d = __builtin_amdgcn_mfma_f32_16x16x32_bf16(a, bf, d, 0, 0, 0);
        }
        #pragma unroll
        for (int r = 0; r < 4; ++r) {
            int row = mt * 16 + kg * 4 + r;
            if (row < 81) en[row * 32 + nt * 16 + l15] = d[r];
        }
    }
    __syncthreads();
}

// ---------------------------------------------------------------------------
// Fused GNN (byte-identical to measured r31/r32: 191 us)
// ---------------------------------------------------------------------------
__global__ __launch_bounds__(TPB, 4) void fused_gnn_kernel(
    const ushort_t* __restrict__ nlb,  // [B][120] bf16
    const ushort_t* __restrict__ elb,  // [B][408] bf16
    const ushort_t* __restrict__ wb,
    const float* __restrict__ ln0_g, const float* __restrict__ ln0_b,
    const float* __restrict__ ln1_g, const float* __restrict__ ln1_b,
    const float* __restrict__ w_feat, const float* __restrict__ w_eout,
    float* __restrict__ out)
{
    __shared__ __align__(16) ushort_t xsb[16 * 40];
    __shared__ __align__(16) ushort_t esb[96 * 40];
    __shared__ __align__(16) ushort_t qb[16 * 132];
    __shared__ __align__(16) ushort_t kb[16 * 132];
    __shared__ __align__(16) ushort_t vb[16 * 132];
    __shared__ __align__(16) ushort_t ehb[96 * 132];
    __shared__ __align__(16) float la[324];
    __shared__ __align__(16) float wfT[10 * 32];
    __shared__ __align__(16) float weT[5 * 32];

    float* en = (float*)ehb;
    float* xn = (float*)qb;

    const int b   = blockIdx.x;
    const int tid = threadIdx.x;

    for (int idx = tid; idx < 16 * 40; idx += TPB) xsb[idx] = 0;
    for (int idx = tid; idx < 96 * 40; idx += TPB) esb[idx] = 0;
    for (int idx = tid; idx < 320; idx += TPB) {
        int c = idx >> 5, kk = idx & 31;
        wfT[idx] = w_feat[kk * 10 + c];
    }
    for (int idx = tid; idx < 160; idx += TPB) {
        int c = idx >> 5, kk = idx & 31;
        weT[idx] = w_eout[kk * 5 + c];
    }
    __syncthreads();
    for (int idx = tid; idx < 117; idx += TPB) {
        int node = idx / 13, m = idx - node * 13;
        xsb[node * 40 + m] = nlb[b * 120 + idx];
    }
    for (int idx = tid; idx < 405; idx += TPB) {
        int le = idx / 5, c = idx - le * 5;
        int i = le / 9, j = le - i * 9;
        esb[le * 40 + c] = f2b(0.5f * (b2f(elb[b * 408 + c * 81 + i * 9 + j]) +
                                       b2f(elb[b * 408 + c * 81 + j * 9 + i])));
    }
    __syncthreads();

    for (int layer = 0; layer < 3; ++layer) {
        if (layer == 0)
            conv_layer<13, 5>(xsb, esb,
                              wb + 0, wb + 5120, wb + 10240, wb + 15360, wb + 40960,
                              qb, kb, vb, ehb, en, xn, la, tid);
        else
            conv_layer<32, 32>(xsb, esb,
                               wb + 20480, wb + 25600, wb + 30720, wb + 35840, wb + 44288,
                               qb, kb, vb, ehb, en, xn, la, tid);

        if (layer < 2) {
            const float* g  = (layer == 0) ? ln0_g : ln1_g;
            const float* be = (layer == 0) ? ln0_b : ln1_b;
            if (tid < 288) {
                int j = tid >> 5, c = tid & 31;
                float v = xn[tid];
                float s = v, q = v * v;
                #pragma unroll
                for (int m = 1; m <= 16; m <<= 1) {
                    s += __shfl_xor(s, m, 64);
                    q += __shfl_xor(q, m, 64);
                }
                float mu  = s * (1.f / 32.f);
                float var = q * (1.f / 32.f) - mu * mu;
                float val = (v - mu) / sqrtf(var + 1e-5f);
                val = val * g[c] + be[c];
                xsb[j * 40 + c] = f2b((val > 0.f) ? val : 0.01f * val);
            }
            for (int idx = tid; idx < 648; idx += TPB) {
                int le = idx >> 3, cg = (idx & 7) * 4;
                f32x4 v = *(const f32x4*)&en[le * 32 + cg];
                #pragma unroll
                for (int u = 0; u < 4; ++u) {
                    float x = v[u];
                    esb[le * 40 + cg + u] = f2b((x > 0.f) ? x : 0.01f * x);
                }
            }
            __syncthreads();
        }
    }

    float* out_x  = out;                       // [36864,10]
    float* out_e  = out + 368640;              // [294912,5]
    float* out_ei = out + 1843200;             // [2,294912]
    float* out_b  = out + 2433024;             // [36864]

    for (int idx = tid; idx < 90; idx += TPB) {
        int j = idx / 10, c = idx - j * 10;
        float acc = 0.f;
        #pragma unroll
        for (int kg2 = 0; kg2 < 8; ++kg2) {
            f32x4 xv = *(const f32x4*)&xn[j * 32 + kg2 * 4];
            f32x4 wv = *(const f32x4*)&wfT[c * 32 + kg2 * 4];
            #pragma unroll
            for (int u = 0; u < 4; ++u) acc = fmaf(xv[u], wv[u], acc);
        }
        out_x[(b * 9 + j) * 10 + c] = acc;
    }
    for (int idx = tid; idx < 360; idx += TPB) {
        int r = idx / 5, c = idx - r * 5;
        int i = r >> 3, jj = r & 7;
        int j = jj + (jj >= i ? 1 : 0);
        const float* row = &en[(i * 9 + j) * 32];
        float acc = 0.f;
        #pragma unroll
        for (int kg2 = 0; kg2 < 8; ++kg2) {
            f32x4 ev = *(const f32x4*)&row[kg2 * 4];
            f32x4 wv = *(const f32x4*)&weT[c * 32 + kg2 * 4];
            #pragma unroll
            for (int u = 0; u < 4; ++u) acc = fmaf(ev[u], wv[u], acc);
        }
        out_e[(b * 72 + r) * 5 + c] = acc;
    }
    for (int idx = tid; idx < 72; idx += TPB) {
        int i = idx >> 3, jj = idx & 7;
        int j = jj + (jj >= i ? 1 : 0);
        out_ei[b * 72 + idx]          = (float)(b * 9 + i);
        out_ei[294912 + b * 72 + idx] = (float)(b * 9 + j);
    }
    for (int idx = tid; idx < 9; idx += TPB)
        out_b[b * 9 + idx] = (float)b;
}

// ---------------------------------------------------------------------------
extern "C" void kernel_launch(void* const* d_in, const int* in_sizes, int n_in,
                              void* d_out, int out_size, void* d_ws, size_t ws_size,
                              hipStream_t stream)
{
    const float* latent  = (const float*)d_in[0];
    const float* w_mlp0  = (const float*)d_in[1];
    const float* b_mlp0  = (const float*)d_in[2];
    const float* w_mlp1  = (const float*)d_in[3];
    const float* b_mlp1  = (const float*)d_in[4];
    const float* w_mlp2  = (const float*)d_in[5];
    const float* b_mlp2  = (const float*)d_in[6];
    const float* w_edges = (const float*)d_in[7];
    const float* b_edges = (const float*)d_in[8];
    const float* w_nodes = (const float*)d_in[9];
    const float* b_nodes = (const float*)d_in[10];
    const float* c0_wq   = (const float*)d_in[11];
    const float* c0_wk   = (const float*)d_in[12];
    const float* c0_wv   = (const float*)d_in[13];
    const float* c0_we   = (const float*)d_in[14];
    const float* c0_weo  = (const float*)d_in[15];
    const float* c1_wq   = (const float*)d_in[16];
    const float* c1_wk   = (const float*)d_in[17];
    const float* c1_wv   = (const float*)d_in[18];
    const float* c1_we   = (const float*)d_in[19];
    const float* c1_weo  = (const float*)d_in[20];
    const float* ln0_g   = (const float*)d_in[21];
    const float* ln0_b   = (const float*)d_in[22];
    const float* ln1_g   = (const float*)d_in[23];
    const float* ln1_b   = (const float*)d_in[24];
    const float* w_feat  = (const float*)d_in[25];
    const float* w_eout  = (const float*)d_in[26];

    // Workspace (ushort offsets; all 16B-aligned) -- unchanged from r29/r31/r32
    ushort_t* wsu  = (ushort_t*)d_ws;
    ushort_t* wb   = wsu;
    ushort_t* bt   = wsu + 47616;
    ushort_t* latb = wsu + 522752;
    ushort_t* h0b  = wsu + 1047040;
    ushort_t* h1b  = wsu + 1571328;
    ushort_t* h2b  = wsu + 2619904;
    ushort_t* elb  = wsu + 4717056;
    ushort_t* nlb  = wsu + 6388224;

    float* out = (float*)d_out;

    prep_all_kernel<<<4090, 256, 0, stream>>>(
        w_mlp0, w_mlp1, w_mlp2, w_edges, w_nodes, latent,
        c0_wq, c0_wk, c0_wv, c0_we, c0_weo,
        c1_wq, c1_wk, c1_wv, c1_we, c1_weo,
        bt, latb, wb);

    // MLP chain on MFMA (MT=1, 64-row blocks); L3+L4 fused into one launch
    gemm_mfma_kernel<1><<<64 * 2, 256, 0, stream>>>(latb, bt + 0,     b_mlp0, h0b, 128, 128, 128, 1, 2);
    gemm_mfma_kernel<1><<<64 * 4, 256, 0, stream>>>(h0b,  bt + 16384, b_mlp1, h1b, 128, 256, 256, 1, 4);
    gemm_mfma_kernel<1><<<64 * 8, 256, 0, stream>>>(h1b,  bt + 49152, b_mlp2, h2b, 256, 512, 512, 1, 8);
    gemm_dual_kernel<<<576, 256, 0, stream>>>(h2b, bt + 180224, bt + 409600,
                                              b_edges, b_nodes, elb, nlb);

    fused_gnn_kernel<<<B_, TPB, 0, stream>>>(nlb, elb, wb,
        ln0_g, ln0_b, ln1_g, ln1_b, w_feat, w_eout, out);
}